// Round 9
// baseline (1029.237 us; speedup 1.0000x reference)
//
#include <hip/hip_runtime.h>
#include <cstdint>
#include <cstddef>

#define HD    1024
#define SLOTS 272
#define MEMS  256
#define BATCH 8
#define TT    4096
#define RR    (BATCH*TT)
#define RANKC 10

#define GAMMA 0.92f
#define BETA  0.08f
#define PTS   0.4f

typedef float f32x2 __attribute__((ext_vector_type(2)));
typedef float f32x4 __attribute__((ext_vector_type(4)));
typedef short bf16x8 __attribute__((ext_vector_type(8)));
#define PKFMA(a, b, c) __builtin_elementwise_fma((a), (b), (c))

// ---------------------------------------------------------------------------
// DPP wave64 sum-allreduce: 6 VALU-speed cross-lane adds + readlane broadcast.
// ---------------------------------------------------------------------------
#define DPP_ADD(v, ctrl, rmask)                                                   \
    v += __int_as_float(__builtin_amdgcn_update_dpp(                              \
        0, __float_as_int(v), (ctrl), (rmask), 0xf, true))

__device__ __forceinline__ float wave_sum_bcast(float v)
{
    DPP_ADD(v, 0xB1,  0xf);   // + lane^1
    DPP_ADD(v, 0x4E,  0xf);   // + lane^2
    DPP_ADD(v, 0x141, 0xf);   // row_half_mirror
    DPP_ADD(v, 0x140, 0xf);   // row_mirror
    DPP_ADD(v, 0x142, 0xa);   // row_bcast15
    DPP_ADD(v, 0x143, 0xc);   // row_bcast31 (lane 63 = total)
    return __int_as_float(__builtin_amdgcn_readlane(__float_as_int(v), 63));
}

// fp32 -> bf16 round-to-nearest-even (bit trick), and back.
__device__ __forceinline__ unsigned short f2bf(float f)
{
    unsigned u = __float_as_uint(f);
    u = (u + 0x7FFFu + ((u >> 16) & 1u)) >> 16;
    return (unsigned short)u;
}
__device__ __forceinline__ float bf2f(unsigned short h)
{
    return __uint_as_float((unsigned)h << 16);
}

// ---------------------------------------------------------------------------
// prep: per-slot constants.
// consts: [0]=wr [256]=bg [512]=A [768]=B [1024]=v0re [1280]=v0im
//         [1536]=cos [1792]=sin [2048]=eta.  flags[2]: eps/pred any-nonzero.
// ---------------------------------------------------------------------------
__global__ void prep_kernel(const float* __restrict__ t0re, const float* __restrict__ t0im,
                            const float* __restrict__ eta_raw,
                            const float* __restrict__ trot, const float* __restrict__ w_r,
                            const float* __restrict__ bgate,
                            const float* __restrict__ eps_scale, const float* __restrict__ pred_scale,
                            const float* __restrict__ eps_diag, const float* __restrict__ pred_diag,
                            float* __restrict__ consts, int* __restrict__ flags)
{
    __shared__ float red[MEMS];
    const int s = threadIdx.x;  // 256 threads
    const float tr = t0re[s], ti = t0im[s];
    red[s] = tr * tr + ti * ti;
    __syncthreads();
    for (int off = 128; off > 0; off >>= 1) {
        if (s < off) red[s] += red[s + off];
        __syncthreads();
    }
    const float nrm = sqrtf(fmaxf(red[0], 1e-16f));
    const float eta = log1pf(expf(eta_raw[0]));
    const float rc = cosf(trot[s]), rs = sinf(trot[s]);
    const float c1 = GAMMA + eta * eps_diag[s];
    const float c2 = PTS * pred_diag[s];
    consts[0 * MEMS + s] = 1.0f / (1.0f + expf(-w_r[s]));
    consts[1 * MEMS + s] = 1.0f / (1.0f + expf(-bgate[s]));
    consts[2 * MEMS + s] = c1 * rc - c2 * rs;   // A
    consts[3 * MEMS + s] = c1 * rs + c2 * rc;   // B
    consts[4 * MEMS + s] = tr / nrm;
    consts[5 * MEMS + s] = ti / nrm;
    consts[6 * MEMS + s] = rc;
    consts[7 * MEMS + s] = rs;
    if (s == 0) {
        consts[8 * MEMS] = eta;
        int f1 = 0, f2 = 0;
        for (int k = 0; k < RANKC; ++k) {
            if (eps_scale[k]  != 0.0f) f1 = 1;
            if (pred_scale[k] != 0.0f) f2 = 1;
        }
        flags[0] = f1;
        flags[1] = f2;
    }
}

// ---------------------------------------------------------------------------
// gprep: G[h][k] = bf16(alpha * bg[k] * basis[h][k]), row-major [1024][256]
// (pre-baked B-operand for the MFMA outp; verified R8).
// ---------------------------------------------------------------------------
__global__ void gprep_kernel(const float* __restrict__ basis,
                             const float* __restrict__ alpha_p,
                             const float* __restrict__ consts,
                             unsigned short* __restrict__ G)
{
    const int h = blockIdx.x;          // 0..1023
    const int k = threadIdx.x;         // 0..255
    const float g = alpha_p[0] * consts[MEMS + k] * basis[(size_t)h * SLOTS + k];
    G[(size_t)h * MEMS + k] = f2bf(g);
}

// ---------------------------------------------------------------------------
// qprep: Qh/Ql[n][k] = bf16 hi/lo split of basis[k][n], row-major [256][1024].
// B-operand for the MFMA proj: frag = ONE 16B load; hi+lo carries ~16 mantissa
// bits so 3-term product error ~1e-4 (fp32-class for top-k purposes).
// ---------------------------------------------------------------------------
__global__ void qprep_kernel(const float* __restrict__ basis,
                             unsigned short* __restrict__ Qh,
                             unsigned short* __restrict__ Ql)
{
    const int n = blockIdx.x;          // 0..255
    for (int k = threadIdx.x; k < HD; k += 256) {
        const float q = basis[(size_t)k * SLOTS + n];
        const unsigned short h = f2bf(q);
        Qh[(size_t)n * HD + k] = h;
        Ql[(size_t)n * HD + k] = f2bf(q - bf2f(h));
    }
}

// ---------------------------------------------------------------------------
// proj (MFMA bf16 3-term split) + FUSED top-8 mask.
// Block = 64 rows x 256 cols, 4 waves x (16 rows x 256 cols).  Per K-block of
// 128: 4 hi/lo A-frag pairs from x (in-register split), then 16 col-tiles x
// 4 chunks x {ah*bh, al*bh, ah*bl} MFMAs.  Layouts identical to the
// HW-verified R8 outp (A [m][k] lane m=l&15 k=8*(l>>4)+j; B [n][k] same;
// C/D row=(l>>4)*4+i col=l&15).
// Top-8 per row (dup-counting, same semantics as the R5-verified code): row
// held by 16 lanes x 16 ct values; 4-stage shfl_xor group argmax, 8 rounds.
// ---------------------------------------------------------------------------
__global__ __launch_bounds__(256) void proj_topk_kernel(const float* __restrict__ x,
                                                        const unsigned short* __restrict__ Qh,
                                                        const unsigned short* __restrict__ Ql,
                                                        float* __restrict__ M)
{
    const int tid = threadIdx.x;
    const int w   = tid >> 6;            // wave 0..3
    const int l   = tid & 63;
    const int ln  = l & 15;
    const int lk  = (l >> 4) * 8;        // k base within 32-chunk
    const size_t row0 = (size_t)blockIdx.x * 64 + (size_t)w * 16;

    f32x4 acc[16] = {};                  // [col-tile] -> 4 row-regs
    for (int kb = 0; kb < HD; kb += 128) {
        // A-frags: 4 chunks of K=32, hi/lo split in-register
        bf16x8 ah[4], al[4];
        {
            const float* xr = &x[(row0 + ln) * HD + kb + lk];
#pragma unroll
            for (int c = 0; c < 4; ++c) {
                const float4 a0 = *(const float4*)&xr[c * 32];
                const float4 a1 = *(const float4*)&xr[c * 32 + 4];
                const float av[8] = {a0.x, a0.y, a0.z, a0.w, a1.x, a1.y, a1.z, a1.w};
                bf16x8 h, lo;
#pragma unroll
                for (int j = 0; j < 8; ++j) {
                    const unsigned short hb = f2bf(av[j]);
                    h[j]  = (short)hb;
                    lo[j] = (short)f2bf(av[j] - bf2f(hb));
                }
                ah[c] = h; al[c] = lo;
            }
        }
#pragma unroll
        for (int ct = 0; ct < 16; ++ct) {
            const unsigned short* qhp = &Qh[(size_t)(ct * 16 + ln) * HD + kb + lk];
            const unsigned short* qlp = &Ql[(size_t)(ct * 16 + ln) * HD + kb + lk];
            f32x4 a = acc[ct];
#pragma unroll
            for (int c = 0; c < 4; ++c) {
                const bf16x8 bh = *(const bf16x8*)&qhp[c * 32];
                const bf16x8 bl = *(const bf16x8*)&qlp[c * 32];
                a = __builtin_amdgcn_mfma_f32_16x16x32_bf16(ah[c], bh, a, 0, 0, 0);
                a = __builtin_amdgcn_mfma_f32_16x16x32_bf16(al[c], bh, a, 0, 0, 0);
                a = __builtin_amdgcn_mfma_f32_16x16x32_bf16(ah[c], bl, a, 0, 0, 0);
            }
            acc[ct] = a;
        }
    }
    // ---- fused top-8 threshold + mask + store ----
#pragma unroll
    for (int i = 0; i < 4; ++i) {
        float v16[16], a16[16], w16[16];
#pragma unroll
        for (int ct = 0; ct < 16; ++ct) {
            v16[ct] = acc[ct][i];
            a16[ct] = fabsf(v16[ct]);
            w16[ct] = a16[ct];
        }
        float kv = 0.0f;
#pragma unroll
        for (int it = 0; it < 8; ++it) {
            float lm = w16[0]; int li = 0;
#pragma unroll
            for (int e = 1; e < 16; ++e)
                if (w16[e] > lm) { lm = w16[e]; li = e; }
            float bm = lm; int bi = ln * 16 + li;
#pragma unroll
            for (int off = 1; off < 16; off <<= 1) {
                const float om = __shfl_xor(bm, off);
                const int   oi = __shfl_xor(bi, off);
                if (om > bm || (om == bm && oi < bi)) { bm = om; bi = oi; }
            }
            kv = bm;
            if ((bi >> 4) == ln) w16[bi & 15] = -1.0f;
        }
        const size_t r = row0 + (size_t)((l >> 4) * 4 + i);
#pragma unroll
        for (int ct = 0; ct < 16; ++ct)
            M[r * MEMS + ct * 16 + ln] = (a16[ct] >= kv) ? BETA * v16[ct] : 0.0f;
    }
}

// ---------------------------------------------------------------------------
// scan: R2-exact (measured 387us; chain-bound optimum of tried formulations).
// ---------------------------------------------------------------------------
__global__ __launch_bounds__(64) void scan_kernel(const float* __restrict__ M,
                                                  const float* __restrict__ consts,
                                                  const int* __restrict__ flags,
                                                  const float* __restrict__ eps_fac,
                                                  const float* __restrict__ eps_scale,
                                                  const float* __restrict__ eps_diag,
                                                  const float* __restrict__ pred_fac,
                                                  const float* __restrict__ pred_scale,
                                                  const float* __restrict__ pred_diag,
                                                  float* __restrict__ Wout)
{
    const int b    = blockIdx.x;
    const int lane = threadIdx.x;
    const int s0   = lane * 4;
    const int general = flags[0] | flags[1];
    const size_t base = (size_t)b * TT * MEMS + s0;

    if (!general) {
        // ---------------- FAST PATH (deferred norm) ----------------
        f32x2 wrg[2], A2[2], B2[2];
        f32x2 wre[2], wim[2], qre[2], qim[2];
        {
            const float4 w4 = *(const float4*)&consts[0 * MEMS + s0];
            const float4 a4 = *(const float4*)&consts[2 * MEMS + s0];
            const float4 b4 = *(const float4*)&consts[3 * MEMS + s0];
            const float4 r4 = *(const float4*)&consts[4 * MEMS + s0];
            const float4 i4 = *(const float4*)&consts[5 * MEMS + s0];
            wrg[0] = {w4.x, w4.y};  wrg[1] = {w4.z, w4.w};
            A2[0]  = {a4.x, a4.y};  A2[1]  = {a4.z, a4.w};
            B2[0]  = {b4.x, b4.y};  B2[1]  = {b4.z, b4.w};
            wre[0] = {r4.x, r4.y};  wre[1] = {r4.z, r4.w};
            wim[0] = {i4.x, i4.y};  wim[1] = {i4.z, i4.w};
            qre[0] = wre[0]; qre[1] = wre[1];
            qim[0] = wim[0]; qim[1] = wim[1];
        }
        float ssp;
        {
            const f32x2 p0 = PKFMA(wim[0], wim[0], wre[0] * wre[0]);
            const f32x2 p1 = PKFMA(wim[1], wim[1], wre[1] * wre[1]);
            const f32x2 pp = p0 + p1;
            ssp = pp.x + pp.y;
        }
        float4 mbuf[16];
#pragma unroll
        for (int j = 0; j < 16; ++j)
            mbuf[j] = *(const float4*)&M[base + (size_t)j * MEMS];
        for (int t0 = 0; t0 < TT; t0 += 16) {
#pragma unroll
            for (int j = 0; j < 16; ++j) {
                const int t = t0 + j;
                const float4 mc = mbuf[j];
                mbuf[j] = *(const float4*)&M[base + (size_t)(t + 16) * MEMS];
                const float stot = wave_sum_bcast(ssp);
                const float icv  = __builtin_amdgcn_rsqf(fmaxf(stot, 1e-16f));
                const f32x2 ic2  = {icv, icv};
                const f32x2 Lr0 = PKFMA(A2[0], wre[0], -(B2[0] * wim[0]));
                const f32x2 Li0 = PKFMA(B2[0], wre[0],  A2[0] * wim[0]);
                const f32x2 Lr1 = PKFMA(A2[1], wre[1], -(B2[1] * wim[1]));
                const f32x2 Li1 = PKFMA(B2[1], wre[1],  A2[1] * wim[1]);
                const f32x2 m0 = {mc.x, mc.y};
                const f32x2 m1 = {mc.z, mc.w};
                const f32x2 Wr0 = PKFMA(wrg[0], qre[0], m0);
                const f32x2 Wi0 = wrg[0] * qim[0];
                const f32x2 Wr1 = PKFMA(wrg[1], qre[1], m1);
                const f32x2 Wi1 = wrg[1] * qim[1];
                const f32x2 u1r0 = PKFMA(ic2, Lr0, Wr0);
                const f32x2 u1i0 = PKFMA(ic2, Li0, Wi0);
                const f32x2 u1r1 = PKFMA(ic2, Lr1, Wr1);
                const f32x2 u1i1 = PKFMA(ic2, Li1, Wi1);
                const f32x2 ps0 = PKFMA(u1i0, u1i0, u1r0 * u1r0);
                const f32x2 ps1 = PKFMA(u1i1, u1i1, u1r1 * u1r1);
                const f32x2 pp  = ps0 + ps1;
                const f32x2 nr0 = wre[0] * ic2, ni0 = wim[0] * ic2;
                const f32x2 nr1 = wre[1] * ic2, ni1 = wim[1] * ic2;
                const int trow = t ? (t - 1) : 0;
                const float4 st4 = {nr0.x, nr0.y, nr1.x, nr1.y};
                *(float4*)&Wout[base + (size_t)trow * MEMS] = st4;
                qre[0] = nr0;  qim[0] = ni0;  qre[1] = nr1;  qim[1] = ni1;
                wre[0] = u1r0; wim[0] = u1i0; wre[1] = u1r1; wim[1] = u1i1;
                ssp = pp.x + pp.y;
            }
        }
        {
            const float stot = wave_sum_bcast(ssp);
            const float icv  = __builtin_amdgcn_rsqf(fmaxf(stot, 1e-16f));
            const float4 wq4 = {wre[0].x * icv, wre[0].y * icv,
                                wre[1].x * icv, wre[1].y * icv};
            *(float4*)&Wout[base + (size_t)(TT - 1) * MEMS] = wq4;
        }
        return;
    }

    // ---------------- GENERAL PATH (R2 verbatim) ----------------
    float wr4[4], ur[4], ui[4], pr[4], pi[4];
    float rc4[4], rs4[4], ed4[4], pd4[4];
#pragma unroll
    for (int i = 0; i < 4; ++i) {
        wr4[i] = consts[0 * MEMS + s0 + i];
        ur[i]  = consts[4 * MEMS + s0 + i];
        ui[i]  = consts[5 * MEMS + s0 + i];
        pr[i] = ur[i]; pi[i] = ui[i];
        rc4[i] = consts[6 * MEMS + s0 + i];
        rs4[i] = consts[7 * MEMS + s0 + i];
        ed4[i] = eps_diag[s0 + i];
        pd4[i] = pred_diag[s0 + i];
    }
    const float eta  = consts[8 * MEMS];
    const int es_any = flags[0];
    const int ps_any = flags[1];
    float4 mbuf[4];
#pragma unroll
    for (int j = 0; j < 4; ++j)
        mbuf[j] = *(const float4*)&M[base + (size_t)j * MEMS];
    for (int t0 = 0; t0 < TT; t0 += 4) {
#pragma unroll
        for (int j = 0; j < 4; ++j) {
            const int t = t0 + j;
            const float4 mc = mbuf[j];
            const int pft = (t + 4 < TT) ? (t + 4) : (TT - 1);
            mbuf[j] = *(const float4*)&M[base + (size_t)pft * MEMS];
            float rr[4], ri[4], nr[4], ni[4];
#pragma unroll
            for (int i = 0; i < 4; ++i) {
                rr[i] = ur[i] * rc4[i] - ui[i] * rs4[i];
                ri[i] = ur[i] * rs4[i] + ui[i] * rc4[i];
            }
            const float mv[4] = {mc.x, mc.y, mc.z, mc.w};
#pragma unroll
            for (int i = 0; i < 4; ++i) {
                nr[i] = GAMMA * rr[i] + wr4[i] * pr[i] + eta * ed4[i] * rr[i]
                        - PTS * pd4[i] * ri[i] + mv[i];   // mv already BETA*inj
                ni[i] = GAMMA * ri[i] + wr4[i] * pi[i] + eta * ed4[i] * ri[i]
                        + PTS * pd4[i] * rr[i];
            }
            if (es_any) {
#pragma unroll
                for (int k = 0; k < RANKC; ++k) {
                    float u[4], prj = 0.0f, pij = 0.0f;
#pragma unroll
                    for (int i = 0; i < 4; ++i) {
                        u[i] = eps_fac[(size_t)(s0 + i) * RANKC + k];
                        prj = fmaf(u[i], rr[i], prj);
                        pij = fmaf(u[i], ri[i], pij);
                    }
                    prj = wave_sum_bcast(prj);
                    pij = wave_sum_bcast(pij);
                    const float sc = eta * eps_scale[k];
#pragma unroll
                    for (int i = 0; i < 4; ++i) {
                        nr[i] = fmaf(sc * u[i], prj, nr[i]);
                        ni[i] = fmaf(sc * u[i], pij, ni[i]);
                    }
                }
            }
            if (ps_any) {
#pragma unroll
                for (int k = 0; k < RANKC; ++k) {
                    float u[4], qrj = 0.0f, qij = 0.0f;
#pragma unroll
                    for (int i = 0; i < 4; ++i) {
                        u[i] = pred_fac[(size_t)(s0 + i) * RANKC + k];
                        qrj = fmaf(u[i], rr[i], qrj);
                        qij = fmaf(u[i], ri[i], qij);
                    }
                    qrj = wave_sum_bcast(qrj);
                    qij = wave_sum_bcast(qij);
                    const float sc = PTS * pred_scale[k];
#pragma unroll
                    for (int i = 0; i < 4; ++i) {
                        nr[i] = fmaf(-sc * u[i], qij, nr[i]);
                        ni[i] = fmaf( sc * u[i], qrj, ni[i]);
                    }
                }
            }
            float ss = 0.0f;
#pragma unroll
            for (int i = 0; i < 4; ++i) ss = fmaf(nr[i], nr[i], fmaf(ni[i], ni[i], ss));
            ss = wave_sum_bcast(ss);
            const float inv = __builtin_amdgcn_rsqf(fmaxf(ss, 1e-16f));
#pragma unroll
            for (int i = 0; i < 4; ++i) {
                pr[i] = ur[i]; pi[i] = ui[i];
                ur[i] = nr[i] * inv; ui[i] = ni[i] * inv;
            }
            const float4 wq = {ur[0], ur[1], ur[2], ur[3]};
            *(float4*)&Wout[base + (size_t)t * MEMS] = wq;
        }
    }
}

// ---------------------------------------------------------------------------
// outp (MFMA bf16, harness-verified R8): Y = X + W * G.
// ---------------------------------------------------------------------------
__global__ __launch_bounds__(256) void outp_kernel(const float* __restrict__ W,
                                                   const unsigned short* __restrict__ G,
                                                   const float* __restrict__ x,
                                                   float* __restrict__ y)
{
    const int tid = threadIdx.x;
    const int w   = tid >> 6;          // wave 0..3
    const int l   = tid & 63;
    const int ln  = l & 15;
    const int lk  = (l >> 4) * 8;      // k base within 32-chunk
    const size_t row0 = (size_t)blockIdx.x * 64 + (size_t)w * 16;
    const int col0 = blockIdx.y * 256;

    bf16x8 af[8];
    {
        const float* wrow = &W[(row0 + ln) * MEMS];
#pragma unroll
        for (int c = 0; c < 8; ++c) {
            const float4 a0 = *(const float4*)&wrow[c * 32 + lk];
            const float4 a1 = *(const float4*)&wrow[c * 32 + lk + 4];
            bf16x8 f;
            f[0] = (short)f2bf(a0.x); f[1] = (short)f2bf(a0.y);
            f[2] = (short)f2bf(a0.z); f[3] = (short)f2bf(a0.w);
            f[4] = (short)f2bf(a1.x); f[5] = (short)f2bf(a1.y);
            f[6] = (short)f2bf(a1.z); f[7] = (short)f2bf(a1.w);
            af[c] = f;
        }
    }
#pragma unroll
    for (int ct = 0; ct < 16; ++ct) {
        const int h = col0 + ct * 16 + ln;
        const unsigned short* grow = &G[(size_t)h * MEMS + lk];
        f32x4 acc = {0.0f, 0.0f, 0.0f, 0.0f};
#pragma unroll
        for (int c = 0; c < 8; ++c) {
            const bf16x8 bf = *(const bf16x8*)&grow[c * 32];
            acc = __builtin_amdgcn_mfma_f32_16x16x32_bf16(af[c], bf, acc, 0, 0, 0);
        }
        const size_t rbase = (row0 + (size_t)((l >> 4) * 4)) * HD + h;
#pragma unroll
        for (int i = 0; i < 4; ++i) {
            const size_t ro = rbase + (size_t)i * HD;
            y[ro] = x[ro] + acc[i];
        }
    }
}

// ---------------------------------------------------------------------------
extern "C" void kernel_launch(void* const* d_in, const int* in_sizes, int n_in,
                              void* d_out, int out_size, void* d_ws, size_t ws_size,
                              hipStream_t stream)
{
    const float* x          = (const float*)d_in[0];
    const float* basis      = (const float*)d_in[1];
    const float* t0re       = (const float*)d_in[2];
    const float* t0im       = (const float*)d_in[3];
    const float* eta_raw    = (const float*)d_in[4];
    const float* alpha      = (const float*)d_in[5];
    const float* trot       = (const float*)d_in[6];
    const float* w_r        = (const float*)d_in[7];
    const float* bgate      = (const float*)d_in[8];
    const float* eps_fac    = (const float*)d_in[9];
    const float* eps_scale  = (const float*)d_in[10];
    const float* eps_diag   = (const float*)d_in[11];
    const float* pred_fac   = (const float*)d_in[12];
    const float* pred_scale = (const float*)d_in[13];
    const float* pred_diag  = (const float*)d_in[14];
    float* out = (float*)d_out;

    const size_t szM = (size_t)RR * MEMS * sizeof(float);   // 32 MB
    const size_t szW = szM;                                  // 32 MB
    const size_t szC = 16384;                                // consts + flags
    const size_t szG = (size_t)HD * MEMS * 2;                // 512 KB bf16 G
    const size_t szQ = (size_t)MEMS * HD * 2;                // 512 KB each Qh/Ql

    char* ws = (char*)d_ws;
    float *Mbuf, *Wbuf, *cbuf;
    unsigned short *Gbuf, *Qhbuf, *Qlbuf;
    if (ws_size >= szM + szW + szC + szG + 2 * szQ) {
        Mbuf  = (float*)(ws);
        Wbuf  = (float*)(ws + szM);
        cbuf  = (float*)(ws + szM + szW);
        Gbuf  = (unsigned short*)(ws + szM + szW + szC);
        Qhbuf = (unsigned short*)(ws + szM + szW + szC + szG);
        Qlbuf = (unsigned short*)(ws + szM + szW + szC + szG + szQ);
    } else {
        // fallback: stage M in d_out (fully consumed by scan before outp
        // rewrites d_out with Y).  G/Qh/Ql stay in ws (read during outp).
        Mbuf  = (float*)d_out;
        Wbuf  = (float*)(ws);
        cbuf  = (float*)(ws + szW);
        Gbuf  = (unsigned short*)(ws + szW + szC);
        Qhbuf = (unsigned short*)(ws + szW + szC + szG);
        Qlbuf = (unsigned short*)(ws + szW + szC + szG + szQ);
    }
    int* fbuf = (int*)(cbuf + 8 * MEMS + 16);

    prep_kernel<<<1, 256, 0, stream>>>(t0re, t0im, eta_raw, trot, w_r, bgate,
                                       eps_scale, pred_scale, eps_diag, pred_diag,
                                       cbuf, fbuf);
    gprep_kernel<<<HD, 256, 0, stream>>>(basis, alpha, cbuf, Gbuf);
    qprep_kernel<<<MEMS, 256, 0, stream>>>(basis, Qhbuf, Qlbuf);
    proj_topk_kernel<<<RR / 64, 256, 0, stream>>>(x, Qhbuf, Qlbuf, Mbuf);
    scan_kernel<<<BATCH, 64, 0, stream>>>(Mbuf, cbuf, fbuf,
                                          eps_fac, eps_scale, eps_diag,
                                          pred_fac, pred_scale, pred_diag,
                                          Wbuf);
    outp_kernel<<<dim3(RR / 64, HD / 256), 256, 0, stream>>>(Wbuf, Gbuf, x, out);
}

// Round 10
// 899.580 us; speedup vs baseline: 1.1441x; 1.1441x over previous
//
#include <hip/hip_runtime.h>
#include <cstdint>
#include <cstddef>

#define HD    1024
#define SLOTS 272
#define MEMS  256
#define BATCH 8
#define TT    4096
#define RR    (BATCH*TT)
#define RANKC 10

#define GAMMA 0.92f
#define BETA  0.08f
#define PTS   0.4f

typedef float f32x2 __attribute__((ext_vector_type(2)));
typedef float f32x4 __attribute__((ext_vector_type(4)));
typedef short bf16x8 __attribute__((ext_vector_type(8)));
#define PKFMA(a, b, c) __builtin_elementwise_fma((a), (b), (c))

// ---------------------------------------------------------------------------
// DPP wave64 sum-allreduce: 6 VALU-speed cross-lane adds + readlane broadcast.
// ---------------------------------------------------------------------------
#define DPP_ADD(v, ctrl, rmask)                                                   \
    v += __int_as_float(__builtin_amdgcn_update_dpp(                              \
        0, __float_as_int(v), (ctrl), (rmask), 0xf, true))

__device__ __forceinline__ float wave_sum_bcast(float v)
{
    DPP_ADD(v, 0xB1,  0xf);   // + lane^1
    DPP_ADD(v, 0x4E,  0xf);   // + lane^2
    DPP_ADD(v, 0x141, 0xf);   // row_half_mirror
    DPP_ADD(v, 0x140, 0xf);   // row_mirror
    DPP_ADD(v, 0x142, 0xa);   // row_bcast15
    DPP_ADD(v, 0x143, 0xc);   // row_bcast31 (lane 63 = total)
    return __int_as_float(__builtin_amdgcn_readlane(__float_as_int(v), 63));
}

// fp32 -> bf16 round-to-nearest-even (bit trick), and back.
__device__ __forceinline__ unsigned short f2bf(float f)
{
    unsigned u = __float_as_uint(f);
    u = (u + 0x7FFFu + ((u >> 16) & 1u)) >> 16;
    return (unsigned short)u;
}
__device__ __forceinline__ float bf2f(unsigned short h)
{
    return __uint_as_float((unsigned)h << 16);
}

// ---------------------------------------------------------------------------
// prep: per-slot constants.
// consts: [0]=wr [256]=bg [512]=A [768]=B [1024]=v0re [1280]=v0im
//         [1536]=cos [1792]=sin [2048]=eta.  flags[2]: eps/pred any-nonzero.
// ---------------------------------------------------------------------------
__global__ void prep_kernel(const float* __restrict__ t0re, const float* __restrict__ t0im,
                            const float* __restrict__ eta_raw,
                            const float* __restrict__ trot, const float* __restrict__ w_r,
                            const float* __restrict__ bgate,
                            const float* __restrict__ eps_scale, const float* __restrict__ pred_scale,
                            const float* __restrict__ eps_diag, const float* __restrict__ pred_diag,
                            float* __restrict__ consts, int* __restrict__ flags)
{
    __shared__ float red[MEMS];
    const int s = threadIdx.x;  // 256 threads
    const float tr = t0re[s], ti = t0im[s];
    red[s] = tr * tr + ti * ti;
    __syncthreads();
    for (int off = 128; off > 0; off >>= 1) {
        if (s < off) red[s] += red[s + off];
        __syncthreads();
    }
    const float nrm = sqrtf(fmaxf(red[0], 1e-16f));
    const float eta = log1pf(expf(eta_raw[0]));
    const float rc = cosf(trot[s]), rs = sinf(trot[s]);
    const float c1 = GAMMA + eta * eps_diag[s];
    const float c2 = PTS * pred_diag[s];
    consts[0 * MEMS + s] = 1.0f / (1.0f + expf(-w_r[s]));
    consts[1 * MEMS + s] = 1.0f / (1.0f + expf(-bgate[s]));
    consts[2 * MEMS + s] = c1 * rc - c2 * rs;   // A
    consts[3 * MEMS + s] = c1 * rs + c2 * rc;   // B
    consts[4 * MEMS + s] = tr / nrm;
    consts[5 * MEMS + s] = ti / nrm;
    consts[6 * MEMS + s] = rc;
    consts[7 * MEMS + s] = rs;
    if (s == 0) {
        consts[8 * MEMS] = eta;
        int f1 = 0, f2 = 0;
        for (int k = 0; k < RANKC; ++k) {
            if (eps_scale[k]  != 0.0f) f1 = 1;
            if (pred_scale[k] != 0.0f) f2 = 1;
        }
        flags[0] = f1;
        flags[1] = f2;
    }
}

// ---------------------------------------------------------------------------
// gprep: G[h][k] = bf16(alpha * bg[k] * basis[h][k]), row-major [1024][256]
// (pre-baked B-operand for the MFMA outp; verified R8).
// ---------------------------------------------------------------------------
__global__ void gprep_kernel(const float* __restrict__ basis,
                             const float* __restrict__ alpha_p,
                             const float* __restrict__ consts,
                             unsigned short* __restrict__ G)
{
    const int h = blockIdx.x;          // 0..1023
    const int k = threadIdx.x;         // 0..255
    const float g = alpha_p[0] * consts[MEMS + k] * basis[(size_t)h * SLOTS + k];
    G[(size_t)h * MEMS + k] = f2bf(g);
}

// ---------------------------------------------------------------------------
// qprep: Qh/Ql[n][k] = bf16 hi/lo split of basis[k][n], row-major [256][1024].
// ---------------------------------------------------------------------------
__global__ void qprep_kernel(const float* __restrict__ basis,
                             unsigned short* __restrict__ Qh,
                             unsigned short* __restrict__ Ql)
{
    const int n = blockIdx.x;          // 0..255
    for (int k = threadIdx.x; k < HD; k += 256) {
        const float q = basis[(size_t)k * SLOTS + n];
        const unsigned short h = f2bf(q);
        Qh[(size_t)n * HD + k] = h;
        Ql[(size_t)n * HD + k] = f2bf(q - bf2f(h));
    }
}

// ---------------------------------------------------------------------------
// proj (MFMA bf16 3-term split, LDS-staged Q) + FUSED top-8 mask.
// R9's version passed but re-read 2 GB of Q from L2 (1 MB per wave per kb);
// this version stages each kb=64 Q-chunk in LDS ONCE per block (64 KB,
// 2 blocks/CU), amortized over 4 waves -> Q L2 traffic 2 GB -> 512 MB.
// LDS layout [c][n][g][8] makes the wave's staging write AND the MFMA
// fragment read each a CONTIGUOUS 1 KB (addr = ln*64+g*16 spans 0..1023) --
// the conflict-free optimum for ds_*_b128.  MFMA math, layouts and top-k
// epilogue are byte-identical to the R9-verified kernel.
// ---------------------------------------------------------------------------
__global__ __launch_bounds__(256) void proj_topk_kernel(const float* __restrict__ x,
                                                        const unsigned short* __restrict__ Qh,
                                                        const unsigned short* __restrict__ Ql,
                                                        float* __restrict__ M)
{
    __shared__ unsigned short QsH[2 * 256 * 4 * 8];   // [c][n][g][8] bf16, 32 KB
    __shared__ unsigned short QsL[2 * 256 * 4 * 8];   // 32 KB
    const int tid = threadIdx.x;
    const int w   = tid >> 6;            // wave 0..3
    const int l   = tid & 63;
    const int ln  = l & 15;
    const int g   = l >> 4;              // 0..3
    const int lk  = g * 8;               // k base within 32-chunk
    const size_t row0 = (size_t)blockIdx.x * 64 + (size_t)w * 16;

    f32x4 acc[16] = {};                  // [col-tile] -> 4 row-regs
    for (int kb = 0; kb < HD; kb += 64) {
        __syncthreads();                 // previous compute done before overwrite
        // ---- stage Q chunk [256 n][64 k] -> [c][n][g][8]; global reads are
        //      128B-contiguous per 8-thread group; LDS writes contiguous 512B/half-wave
#pragma unroll
        for (int i = 0; i < 8; ++i) {
            const int idx = i * 256 + tid;          // 0..2047
            const int n   = idx >> 3;               // 0..255
            const int sub = idx & 7;                // 16B unit within 64-k chunk
            const int c   = sub >> 2;               // K32 chunk 0..1
            const int gg  = sub & 3;
            const size_t goff = (size_t)n * HD + kb + sub * 8;
            const int     lof = ((c * 256 + n) * 4 + gg) * 8;
            *(bf16x8*)&QsH[lof] = *(const bf16x8*)&Qh[goff];
            *(bf16x8*)&QsL[lof] = *(const bf16x8*)&Ql[goff];
        }
        __syncthreads();
        // ---- A-frags: 2 chunks of K=32, hi/lo split in-register (R9-verbatim)
        bf16x8 ah[2], al[2];
        {
            const float* xr = &x[(row0 + ln) * HD + kb + lk];
#pragma unroll
            for (int c = 0; c < 2; ++c) {
                const float4 a0 = *(const float4*)&xr[c * 32];
                const float4 a1 = *(const float4*)&xr[c * 32 + 4];
                const float av[8] = {a0.x, a0.y, a0.z, a0.w, a1.x, a1.y, a1.z, a1.w};
                bf16x8 h, lo;
#pragma unroll
                for (int j = 0; j < 8; ++j) {
                    const unsigned short hb = f2bf(av[j]);
                    h[j]  = (short)hb;
                    lo[j] = (short)f2bf(av[j] - bf2f(hb));
                }
                ah[c] = h; al[c] = lo;
            }
        }
#pragma unroll
        for (int ct = 0; ct < 16; ++ct) {
            f32x4 a = acc[ct];
#pragma unroll
            for (int c = 0; c < 2; ++c) {
                const int lof = ((c * 256 + ct * 16 + ln) * 4 + g) * 8;
                const bf16x8 bh = *(const bf16x8*)&QsH[lof];
                const bf16x8 bl = *(const bf16x8*)&QsL[lof];
                a = __builtin_amdgcn_mfma_f32_16x16x32_bf16(ah[c], bh, a, 0, 0, 0);
                a = __builtin_amdgcn_mfma_f32_16x16x32_bf16(al[c], bh, a, 0, 0, 0);
                a = __builtin_amdgcn_mfma_f32_16x16x32_bf16(ah[c], bl, a, 0, 0, 0);
            }
            acc[ct] = a;
        }
    }
    // ---- fused top-8 threshold + mask + store (R9-verified verbatim) ----
#pragma unroll
    for (int i = 0; i < 4; ++i) {
        float v16[16], a16[16], w16[16];
#pragma unroll
        for (int ct = 0; ct < 16; ++ct) {
            v16[ct] = acc[ct][i];
            a16[ct] = fabsf(v16[ct]);
            w16[ct] = a16[ct];
        }
        float kv = 0.0f;
#pragma unroll
        for (int it = 0; it < 8; ++it) {
            float lm = w16[0]; int li = 0;
#pragma unroll
            for (int e = 1; e < 16; ++e)
                if (w16[e] > lm) { lm = w16[e]; li = e; }
            float bm = lm; int bi = ln * 16 + li;
#pragma unroll
            for (int off = 1; off < 16; off <<= 1) {
                const float om = __shfl_xor(bm, off);
                const int   oi = __shfl_xor(bi, off);
                if (om > bm || (om == bm && oi < bi)) { bm = om; bi = oi; }
            }
            kv = bm;
            if ((bi >> 4) == ln) w16[bi & 15] = -1.0f;
        }
        const size_t r = row0 + (size_t)((l >> 4) * 4 + i);
#pragma unroll
        for (int ct = 0; ct < 16; ++ct)
            M[r * MEMS + ct * 16 + ln] = (a16[ct] >= kv) ? BETA * v16[ct] : 0.0f;
    }
}

// ---------------------------------------------------------------------------
// scan: R2-exact (measured 386us; chain-bound optimum of tried formulations).
// ---------------------------------------------------------------------------
__global__ __launch_bounds__(64) void scan_kernel(const float* __restrict__ M,
                                                  const float* __restrict__ consts,
                                                  const int* __restrict__ flags,
                                                  const float* __restrict__ eps_fac,
                                                  const float* __restrict__ eps_scale,
                                                  const float* __restrict__ eps_diag,
                                                  const float* __restrict__ pred_fac,
                                                  const float* __restrict__ pred_scale,
                                                  const float* __restrict__ pred_diag,
                                                  float* __restrict__ Wout)
{
    const int b    = blockIdx.x;
    const int lane = threadIdx.x;
    const int s0   = lane * 4;
    const int general = flags[0] | flags[1];
    const size_t base = (size_t)b * TT * MEMS + s0;

    if (!general) {
        // ---------------- FAST PATH (deferred norm) ----------------
        f32x2 wrg[2], A2[2], B2[2];
        f32x2 wre[2], wim[2], qre[2], qim[2];
        {
            const float4 w4 = *(const float4*)&consts[0 * MEMS + s0];
            const float4 a4 = *(const float4*)&consts[2 * MEMS + s0];
            const float4 b4 = *(const float4*)&consts[3 * MEMS + s0];
            const float4 r4 = *(const float4*)&consts[4 * MEMS + s0];
            const float4 i4 = *(const float4*)&consts[5 * MEMS + s0];
            wrg[0] = {w4.x, w4.y};  wrg[1] = {w4.z, w4.w};
            A2[0]  = {a4.x, a4.y};  A2[1]  = {a4.z, a4.w};
            B2[0]  = {b4.x, b4.y};  B2[1]  = {b4.z, b4.w};
            wre[0] = {r4.x, r4.y};  wre[1] = {r4.z, r4.w};
            wim[0] = {i4.x, i4.y};  wim[1] = {i4.z, i4.w};
            qre[0] = wre[0]; qre[1] = wre[1];
            qim[0] = wim[0]; qim[1] = wim[1];
        }
        float ssp;
        {
            const f32x2 p0 = PKFMA(wim[0], wim[0], wre[0] * wre[0]);
            const f32x2 p1 = PKFMA(wim[1], wim[1], wre[1] * wre[1]);
            const f32x2 pp = p0 + p1;
            ssp = pp.x + pp.y;
        }
        float4 mbuf[16];
#pragma unroll
        for (int j = 0; j < 16; ++j)
            mbuf[j] = *(const float4*)&M[base + (size_t)j * MEMS];
        for (int t0 = 0; t0 < TT; t0 += 16) {
#pragma unroll
            for (int j = 0; j < 16; ++j) {
                const int t = t0 + j;
                const float4 mc = mbuf[j];
                mbuf[j] = *(const float4*)&M[base + (size_t)(t + 16) * MEMS];
                const float stot = wave_sum_bcast(ssp);
                const float icv  = __builtin_amdgcn_rsqf(fmaxf(stot, 1e-16f));
                const f32x2 ic2  = {icv, icv};
                const f32x2 Lr0 = PKFMA(A2[0], wre[0], -(B2[0] * wim[0]));
                const f32x2 Li0 = PKFMA(B2[0], wre[0],  A2[0] * wim[0]);
                const f32x2 Lr1 = PKFMA(A2[1], wre[1], -(B2[1] * wim[1]));
                const f32x2 Li1 = PKFMA(B2[1], wre[1],  A2[1] * wim[1]);
                const f32x2 m0 = {mc.x, mc.y};
                const f32x2 m1 = {mc.z, mc.w};
                const f32x2 Wr0 = PKFMA(wrg[0], qre[0], m0);
                const f32x2 Wi0 = wrg[0] * qim[0];
                const f32x2 Wr1 = PKFMA(wrg[1], qre[1], m1);
                const f32x2 Wi1 = wrg[1] * qim[1];
                const f32x2 u1r0 = PKFMA(ic2, Lr0, Wr0);
                const f32x2 u1i0 = PKFMA(ic2, Li0, Wi0);
                const f32x2 u1r1 = PKFMA(ic2, Lr1, Wr1);
                const f32x2 u1i1 = PKFMA(ic2, Li1, Wi1);
                const f32x2 ps0 = PKFMA(u1i0, u1i0, u1r0 * u1r0);
                const f32x2 ps1 = PKFMA(u1i1, u1i1, u1r1 * u1r1);
                const f32x2 pp  = ps0 + ps1;
                const f32x2 nr0 = wre[0] * ic2, ni0 = wim[0] * ic2;
                const f32x2 nr1 = wre[1] * ic2, ni1 = wim[1] * ic2;
                const int trow = t ? (t - 1) : 0;
                const float4 st4 = {nr0.x, nr0.y, nr1.x, nr1.y};
                *(float4*)&Wout[base + (size_t)trow * MEMS] = st4;
                qre[0] = nr0;  qim[0] = ni0;  qre[1] = nr1;  qim[1] = ni1;
                wre[0] = u1r0; wim[0] = u1i0; wre[1] = u1r1; wim[1] = u1i1;
                ssp = pp.x + pp.y;
            }
        }
        {
            const float stot = wave_sum_bcast(ssp);
            const float icv  = __builtin_amdgcn_rsqf(fmaxf(stot, 1e-16f));
            const float4 wq4 = {wre[0].x * icv, wre[0].y * icv,
                                wre[1].x * icv, wre[1].y * icv};
            *(float4*)&Wout[base + (size_t)(TT - 1) * MEMS] = wq4;
        }
        return;
    }

    // ---------------- GENERAL PATH (R2 verbatim) ----------------
    float wr4[4], ur[4], ui[4], pr[4], pi[4];
    float rc4[4], rs4[4], ed4[4], pd4[4];
#pragma unroll
    for (int i = 0; i < 4; ++i) {
        wr4[i] = consts[0 * MEMS + s0 + i];
        ur[i]  = consts[4 * MEMS + s0 + i];
        ui[i]  = consts[5 * MEMS + s0 + i];
        pr[i] = ur[i]; pi[i] = ui[i];
        rc4[i] = consts[6 * MEMS + s0 + i];
        rs4[i] = consts[7 * MEMS + s0 + i];
        ed4[i] = eps_diag[s0 + i];
        pd4[i] = pred_diag[s0 + i];
    }
    const float eta  = consts[8 * MEMS];
    const int es_any = flags[0];
    const int ps_any = flags[1];
    float4 mbuf[4];
#pragma unroll
    for (int j = 0; j < 4; ++j)
        mbuf[j] = *(const float4*)&M[base + (size_t)j * MEMS];
    for (int t0 = 0; t0 < TT; t0 += 4) {
#pragma unroll
        for (int j = 0; j < 4; ++j) {
            const int t = t0 + j;
            const float4 mc = mbuf[j];
            const int pft = (t + 4 < TT) ? (t + 4) : (TT - 1);
            mbuf[j] = *(const float4*)&M[base + (size_t)pft * MEMS];
            float rr[4], ri[4], nr[4], ni[4];
#pragma unroll
            for (int i = 0; i < 4; ++i) {
                rr[i] = ur[i] * rc4[i] - ui[i] * rs4[i];
                ri[i] = ur[i] * rs4[i] + ui[i] * rc4[i];
            }
            const float mv[4] = {mc.x, mc.y, mc.z, mc.w};
#pragma unroll
            for (int i = 0; i < 4; ++i) {
                nr[i] = GAMMA * rr[i] + wr4[i] * pr[i] + eta * ed4[i] * rr[i]
                        - PTS * pd4[i] * ri[i] + mv[i];   // mv already BETA*inj
                ni[i] = GAMMA * ri[i] + wr4[i] * pi[i] + eta * ed4[i] * ri[i]
                        + PTS * pd4[i] * rr[i];
            }
            if (es_any) {
#pragma unroll
                for (int k = 0; k < RANKC; ++k) {
                    float u[4], prj = 0.0f, pij = 0.0f;
#pragma unroll
                    for (int i = 0; i < 4; ++i) {
                        u[i] = eps_fac[(size_t)(s0 + i) * RANKC + k];
                        prj = fmaf(u[i], rr[i], prj);
                        pij = fmaf(u[i], ri[i], pij);
                    }
                    prj = wave_sum_bcast(prj);
                    pij = wave_sum_bcast(pij);
                    const float sc = eta * eps_scale[k];
#pragma unroll
                    for (int i = 0; i < 4; ++i) {
                        nr[i] = fmaf(sc * u[i], prj, nr[i]);
                        ni[i] = fmaf(sc * u[i], pij, ni[i]);
                    }
                }
            }
            if (ps_any) {
#pragma unroll
                for (int k = 0; k < RANKC; ++k) {
                    float u[4], qrj = 0.0f, qij = 0.0f;
#pragma unroll
                    for (int i = 0; i < 4; ++i) {
                        u[i] = pred_fac[(size_t)(s0 + i) * RANKC + k];
                        qrj = fmaf(u[i], rr[i], qrj);
                        qij = fmaf(u[i], ri[i], qij);
                    }
                    qrj = wave_sum_bcast(qrj);
                    qij = wave_sum_bcast(qij);
                    const float sc = PTS * pred_scale[k];
#pragma unroll
                    for (int i = 0; i < 4; ++i) {
                        nr[i] = fmaf(-sc * u[i], qij, nr[i]);
                        ni[i] = fmaf( sc * u[i], qrj, ni[i]);
                    }
                }
            }
            float ss = 0.0f;
#pragma unroll
            for (int i = 0; i < 4; ++i) ss = fmaf(nr[i], nr[i], fmaf(ni[i], ni[i], ss));
            ss = wave_sum_bcast(ss);
            const float inv = __builtin_amdgcn_rsqf(fmaxf(ss, 1e-16f));
#pragma unroll
            for (int i = 0; i < 4; ++i) {
                pr[i] = ur[i]; pi[i] = ui[i];
                ur[i] = nr[i] * inv; ui[i] = ni[i] * inv;
            }
            const float4 wq = {ur[0], ur[1], ur[2], ur[3]};
            *(float4*)&Wout[base + (size_t)t * MEMS] = wq;
        }
    }
}

// ---------------------------------------------------------------------------
// outp (MFMA bf16, harness-verified R8): Y = X + W * G.
// ---------------------------------------------------------------------------
__global__ __launch_bounds__(256) void outp_kernel(const float* __restrict__ W,
                                                   const unsigned short* __restrict__ G,
                                                   const float* __restrict__ x,
                                                   float* __restrict__ y)
{
    const int tid = threadIdx.x;
    const int w   = tid >> 6;          // wave 0..3
    const int l   = tid & 63;
    const int ln  = l & 15;
    const int lk  = (l >> 4) * 8;      // k base within 32-chunk
    const size_t row0 = (size_t)blockIdx.x * 64 + (size_t)w * 16;
    const int col0 = blockIdx.y * 256;

    bf16x8 af[8];
    {
        const float* wrow = &W[(row0 + ln) * MEMS];
#pragma unroll
        for (int c = 0; c < 8; ++c) {
            const float4 a0 = *(const float4*)&wrow[c * 32 + lk];
            const float4 a1 = *(const float4*)&wrow[c * 32 + lk + 4];
            bf16x8 f;
            f[0] = (short)f2bf(a0.x); f[1] = (short)f2bf(a0.y);
            f[2] = (short)f2bf(a0.z); f[3] = (short)f2bf(a0.w);
            f[4] = (short)f2bf(a1.x); f[5] = (short)f2bf(a1.y);
            f[6] = (short)f2bf(a1.z); f[7] = (short)f2bf(a1.w);
            af[c] = f;
        }
    }
#pragma unroll
    for (int ct = 0; ct < 16; ++ct) {
        const int h = col0 + ct * 16 + ln;
        const unsigned short* grow = &G[(size_t)h * MEMS + lk];
        f32x4 acc = {0.0f, 0.0f, 0.0f, 0.0f};
#pragma unroll
        for (int c = 0; c < 8; ++c) {
            const bf16x8 bf = *(const bf16x8*)&grow[c * 32];
            acc = __builtin_amdgcn_mfma_f32_16x16x32_bf16(af[c], bf, acc, 0, 0, 0);
        }
        const size_t rbase = (row0 + (size_t)((l >> 4) * 4)) * HD + h;
#pragma unroll
        for (int i = 0; i < 4; ++i) {
            const size_t ro = rbase + (size_t)i * HD;
            y[ro] = x[ro] + acc[i];
        }
    }
}

// ---------------------------------------------------------------------------
extern "C" void kernel_launch(void* const* d_in, const int* in_sizes, int n_in,
                              void* d_out, int out_size, void* d_ws, size_t ws_size,
                              hipStream_t stream)
{
    const float* x          = (const float*)d_in[0];
    const float* basis      = (const float*)d_in[1];
    const float* t0re       = (const float*)d_in[2];
    const float* t0im       = (const float*)d_in[3];
    const float* eta_raw    = (const float*)d_in[4];
    const float* alpha      = (const float*)d_in[5];
    const float* trot       = (const float*)d_in[6];
    const float* w_r        = (const float*)d_in[7];
    const float* bgate      = (const float*)d_in[8];
    const float* eps_fac    = (const float*)d_in[9];
    const float* eps_scale  = (const float*)d_in[10];
    const float* eps_diag   = (const float*)d_in[11];
    const float* pred_fac   = (const float*)d_in[12];
    const float* pred_scale = (const float*)d_in[13];
    const float* pred_diag  = (const float*)d_in[14];
    float* out = (float*)d_out;

    const size_t szM = (size_t)RR * MEMS * sizeof(float);   // 32 MB
    const size_t szW = szM;                                  // 32 MB
    const size_t szC = 16384;                                // consts + flags
    const size_t szG = (size_t)HD * MEMS * 2;                // 512 KB bf16 G
    const size_t szQ = (size_t)MEMS * HD * 2;                // 512 KB each Qh/Ql

    char* ws = (char*)d_ws;
    float *Mbuf, *Wbuf, *cbuf;
    unsigned short *Gbuf, *Qhbuf, *Qlbuf;
    if (ws_size >= szM + szW + szC + szG + 2 * szQ) {
        Mbuf  = (float*)(ws);
        Wbuf  = (float*)(ws + szM);
        cbuf  = (float*)(ws + szM + szW);
        Gbuf  = (unsigned short*)(ws + szM + szW + szC);
        Qhbuf = (unsigned short*)(ws + szM + szW + szC + szG);
        Qlbuf = (unsigned short*)(ws + szM + szW + szC + szG + szQ);
    } else {
        // fallback: stage M in d_out (fully consumed by scan before outp
        // rewrites d_out with Y).  G/Qh/Ql stay in ws (read during outp).
        Mbuf  = (float*)d_out;
        Wbuf  = (float*)(ws);
        cbuf  = (float*)(ws + szW);
        Gbuf  = (unsigned short*)(ws + szW + szC);
        Qhbuf = (unsigned short*)(ws + szW + szC + szG);
        Qlbuf = (unsigned short*)(ws + szW + szC + szG + szQ);
    }
    int* fbuf = (int*)(cbuf + 8 * MEMS + 16);

    prep_kernel<<<1, 256, 0, stream>>>(t0re, t0im, eta_raw, trot, w_r, bgate,
                                       eps_scale, pred_scale, eps_diag, pred_diag,
                                       cbuf, fbuf);
    gprep_kernel<<<HD, 256, 0, stream>>>(basis, alpha, cbuf, Gbuf);
    qprep_kernel<<<MEMS, 256, 0, stream>>>(basis, Qhbuf, Qlbuf);
    proj_topk_kernel<<<RR / 64, 256, 0, stream>>>(x, Qhbuf, Qlbuf, Mbuf);
    scan_kernel<<<BATCH, 64, 0, stream>>>(Mbuf, cbuf, fbuf,
                                          eps_fac, eps_scale, eps_diag,
                                          pred_fac, pred_scale, pred_diag,
                                          Wbuf);
    outp_kernel<<<dim3(RR / 64, HD / 256), 256, 0, stream>>>(Wbuf, Gbuf, x, out);
}